// Round 5
// baseline (11178.619 us; speedup 1.0000x reference)
//
#include <hip/hip_runtime.h>
#include <hip/hip_cooperative_groups.h>
#include <cstdint>
#include <cstddef>

#define TT 128
#define BB 64
#define EE 256
#define HH 1024
#define VV 8000

// ---------------- threefry2x32 (20 rounds), bit-exact vs JAX partitionable ----------------
__device__ __forceinline__ uint32_t rotl32(uint32_t v, int r){ return (v<<r)|(v>>(32-r)); }

__device__ __forceinline__ void tf2x32(uint32_t k0, uint32_t k1, uint32_t x0, uint32_t x1,
                                       uint32_t& y0, uint32_t& y1)
{
  const uint32_t k2 = k0 ^ k1 ^ 0x1BD11BDAu;
  x0 += k0; x1 += k1;
#define TFR(r) { x0 += x1; x1 = rotl32(x1,(r)); x1 ^= x0; }
  TFR(13) TFR(15) TFR(26) TFR(6)   x0 += k1; x1 += k2 + 1u;
  TFR(17) TFR(29) TFR(16) TFR(24)  x0 += k2; x1 += k0 + 2u;
  TFR(13) TFR(15) TFR(26) TFR(6)   x0 += k0; x1 += k1 + 3u;
  TFR(17) TFR(29) TFR(16) TFR(24)  x0 += k1; x1 += k2 + 4u;
  TFR(13) TFR(15) TFR(26) TFR(6)   x0 += k2; x1 += k0 + 5u;
#undef TFR
  y0 = x0; y1 = x1;
}

// uniform in [tiny,1): bit-exact fp32 recipe of jax uniform(minval=tiny, maxval=1)
__device__ __forceinline__ float u01f(uint32_t bits){
  float f = __uint_as_float((bits >> 9) | 0x3f800000u) - 1.0f;
  return (f == 0.0f) ? 1.17549435e-38f : f;
}

// ---------------- XLA EmitFastTanh, non-FMA form (mul/add separate roundings) ------------
__device__ __forceinline__ float xla_tanh(float x){
  float xc = fminf(fmaxf(x, -7.90531110763549805f), 7.90531110763549805f);
  float x2 = __fmul_rn(xc, xc);
  float num = -2.76076847742355e-16f;
  num = __fadd_rn(__fmul_rn(x2, num),  2.00018790482477e-13f);
  num = __fadd_rn(__fmul_rn(x2, num), -8.60467152213735e-11f);
  num = __fadd_rn(__fmul_rn(x2, num),  5.12229709037114e-08f);
  num = __fadd_rn(__fmul_rn(x2, num),  1.48572235717979e-05f);
  num = __fadd_rn(__fmul_rn(x2, num),  6.37261928875436e-04f);
  num = __fadd_rn(__fmul_rn(x2, num),  4.89352455891786e-03f);
  num = __fmul_rn(xc, num);
  float den = 1.19825839466702e-06f;
  den = __fadd_rn(__fmul_rn(x2, den), 1.18534705686654e-04f);
  den = __fadd_rn(__fmul_rn(x2, den), 2.26843463243900e-03f);
  den = __fadd_rn(__fmul_rn(x2, den), 4.89352518554385e-03f);
  float r = __fdiv_rn(num, den);
  return (fabsf(x) < 0.0004f) ? x : r;
}

// XLA LogisticExpander: logistic(x) = 0.5 + 0.5*tanh(0.5*x), separate roundings
__device__ __forceinline__ float xla_sigmoid(float x){
  float t = xla_tanh(__fmul_rn(0.5f, x));
  return __fadd_rn(0.5f, __fmul_rn(0.5f, t));
}

// pack fp32 score + v; ties -> smaller v (first-max, matching jnp.argmax)
__device__ __forceinline__ unsigned long long pack32(float s, int v){
  uint32_t u = __float_as_uint(s);
  u = (u >> 31) ? ~u : (u | 0x80000000u);
  return ((unsigned long long)u << 32) | (unsigned)(8191 - v);
}

// ---------------- init ----------------
__global__ void initz(float* ring, unsigned long long* best){
  int i = blockIdx.x*256 + threadIdx.x;
  if (i < 2*HH*BB) ring[i] = 0.f;
  if (i < TT*BB)   best[i] = 0ull;
}

// ---------------- transpose 4 gate matrices: in [R][C] -> out[(g*C + c)*R + r] ----------------
__global__ __launch_bounds__(256) void transpose4f(
    const float* __restrict__ g0, const float* __restrict__ g1,
    const float* __restrict__ g2, const float* __restrict__ g3,
    float* __restrict__ out, int R, int C)
{
  const float* in = (blockIdx.y==0)?g0:(blockIdx.y==1)?g1:(blockIdx.y==2)?g2:g3;
  int tilesC = C >> 6;
  int tr = blockIdx.x / tilesC, tc = blockIdx.x % tilesC;
  __shared__ float tile[64][65];
  int tid = threadIdx.x;
  #pragma unroll
  for (int s = 0; s < 16; ++s) {
    int li = s*256 + tid;
    int r = li >> 6, c = li & 63;
    tile[r][c] = in[(size_t)(tr*64 + r)*C + tc*64 + c];
  }
  __syncthreads();
  #pragma unroll
  for (int s = 0; s < 16; ++s) {
    int li = s*256 + tid;
    int c = li >> 6, r = li & 63;
    out[((size_t)blockIdx.y*C + tc*64 + c)*R + tr*64 + r] = tile[r][c];
  }
}

// ---------------- cooperative LSTM recurrence: XLA-CPU-AVX-f32 faithful --------------------
// 256 blocks x 256 threads (4 waves). Wave w owns gate-row j = bid*4+w; lanes = batch b.
// Per thread (j,b):
//   xw: sequential-e mul+add chain (Eigen AVX no-FMA, K=256 single panel), then one bias add.
//   hU: sequential-k mul+add chains in Eigen kc=288 panels; C = ((P1+P2)+P3)+P4 CR adds.
//   z = fl(xw + hU); gates via XLA fast-tanh / tanh-form logistic; elementwise no-FMA.
__global__ __launch_bounds__(256) void lstm_rec(
    const int* __restrict__ x, const float* __restrict__ emb,
    const float* __restrict__ Wt, const float* __restrict__ Ut,
    const float* __restrict__ bi, const float* __restrict__ bf,
    const float* __restrict__ bog, const float* __restrict__ bc,
    float* __restrict__ ring, float* __restrict__ hist)
{
  __shared__ float lds[128*68];   // 34.8 KB staging, pad 68 vs bank conflicts
  cooperative_groups::grid_group grid = cooperative_groups::this_grid();
  const int tid = threadIdx.x;
  const int w   = tid >> 6;
  const int b   = tid & 63;
  const int ju  = __builtin_amdgcn_readfirstlane(blockIdx.x*4 + w);  // wave-uniform -> s_load

  const float* w0 = Wt + (size_t)(0*HH + ju)*EE;
  const float* w1 = Wt + (size_t)(1*HH + ju)*EE;
  const float* w2 = Wt + (size_t)(2*HH + ju)*EE;
  const float* w3 = Wt + (size_t)(3*HH + ju)*EE;
  const float* u0 = Ut + (size_t)(0*HH + ju)*HH;
  const float* u1 = Ut + (size_t)(1*HH + ju)*HH;
  const float* u2 = Ut + (size_t)(2*HH + ju)*HH;
  const float* u3 = Ut + (size_t)(3*HH + ju)*HH;
  const float bia0 = bi[ju], bia1 = bf[ju], bia2 = bog[ju], bia3 = bc[ju];

  float c = 0.f;

  for (int t = 0; t < TT; ++t) {
    const float* hp = ring + (size_t)(t & 1)*(HH*BB);
    float*       rn = ring + (size_t)((t+1) & 1)*(HH*BB);

    // ---- xw = (px @ Wcat): sequential-e mul+add, single accumulator (K=256 < kc) ----
    float A0 = 0.f, A1 = 0.f, A2 = 0.f, A3 = 0.f;
    for (int ch = 0; ch < 2; ++ch) {
      __syncthreads();
      #pragma unroll
      for (int s = 0; s < 32; ++s) {
        int idx = s*256 + tid;
        int e   = idx & 127;
        int bb  = idx >> 7;
        int tok = x[bb*TT + t];
        lds[e*68 + bb] = emb[(size_t)tok*EE + ch*128 + e];
      }
      __syncthreads();
      #pragma unroll 8
      for (int e = 0; e < 128; ++e) {
        float pv = lds[e*68 + b];
        A0 = __fadd_rn(A0, __fmul_rn(pv, w0[ch*128 + e]));
        A1 = __fadd_rn(A1, __fmul_rn(pv, w1[ch*128 + e]));
        A2 = __fadd_rn(A2, __fmul_rn(pv, w2[ch*128 + e]));
        A3 = __fadd_rn(A3, __fmul_rn(pv, w3[ch*128 + e]));
      }
    }
    // xw = fl(dot + bcat) (reference materializes xw via broadcast add)
    float B0 = __fadd_rn(A0, bia0), B1 = __fadd_rn(A1, bia1);
    float B2 = __fadd_rn(A2, bia2), B3 = __fadd_rn(A3, bia3);

    // ---- h @ Ucat: mul+add chains, Eigen kc=288 panels (folds at k=288,576,864) ----
    float T0=0.f,T1=0.f,T2=0.f,T3=0.f;   // panel totals
    float R0=0.f,R1=0.f,R2=0.f,R3=0.f;   // current panel accumulator
    #pragma unroll 1
    for (int hc = 0; hc < 8; ++hc) {
      __syncthreads();
      #pragma unroll
      for (int s = 0; s < 8; ++s) {
        int f4 = s*256 + tid;
        int kl = f4 >> 4;
        int b0 = (f4 & 15)*4;
        const float4 v4 = *(const float4*)(hp + (size_t)(hc*128 + kl)*BB + b0);
        *(float4*)&lds[kl*68 + b0] = v4;
      }
      __syncthreads();
      #pragma unroll
      for (int sub = 0; sub < 4; ++sub) {
        int kabs = hc*128 + sub*32;
        if (kabs == 288 || kabs == 576 || kabs == 864) {   // Eigen C += panel (CR add)
          T0 = __fadd_rn(T0, R0); R0 = 0.f;
          T1 = __fadd_rn(T1, R1); R1 = 0.f;
          T2 = __fadd_rn(T2, R2); R2 = 0.f;
          T3 = __fadd_rn(T3, R3); R3 = 0.f;
        }
        #pragma unroll 8
        for (int q = sub*32; q < sub*32 + 32; ++q) {
          float hv = lds[q*68 + b];
          R0 = __fadd_rn(R0, __fmul_rn(hv, u0[hc*128 + q]));
          R1 = __fadd_rn(R1, __fmul_rn(hv, u1[hc*128 + q]));
          R2 = __fadd_rn(R2, __fmul_rn(hv, u2[hc*128 + q]));
          R3 = __fadd_rn(R3, __fmul_rn(hv, u3[hc*128 + q]));
        }
      }
    }
    // final panel fold
    T0 = __fadd_rn(T0, R0); T1 = __fadd_rn(T1, R1);
    T2 = __fadd_rn(T2, R2); T3 = __fadd_rn(T3, R3);

    // ---- z = fl(xw + hU); gates: XLA logistic (tanh form) + fast-tanh; no FMA ----
    float zi = __fadd_rn(B0, T0);
    float zf = __fadd_rn(B1, T1);
    float zo = __fadd_rn(B2, T2);
    float zc = __fadd_rn(B3, T3);
    float ig = xla_sigmoid(zi);
    float fg = xla_sigmoid(zf);
    float og = xla_sigmoid(zo);
    float th = xla_tanh(zc);
    float cn = __fadd_rn(__fmul_rn(fg, c), __fmul_rn(ig, th));
    c = cn;
    float hv = __fmul_rn(og, xla_tanh(cn));

    rn[(size_t)ju*BB + b] = hv;
    if (t >= 64) hist[(size_t)(t-64)*(HH*BB) + (size_t)ju*BB + b] = hv;
    grid.sync();
  }
}

// ---------------- logits + gumbel argmax: XLA-CPU-AVX-f32 faithful ----------------
// grid (8 v-tiles of 1024, 64 t, 4 b-quarters), block 256 (4 waves, lanes = v).
// Per lane: 4 v-stripes x 16 b accumulators; mul+add chains in kc=288 panels;
// L = fl(hWo + bo); score = fl(g + L); first-max argmax.
__global__ __launch_bounds__(256, 2) void logits_samp(
    const float* __restrict__ hist, const float* __restrict__ Wo,
    const float* __restrict__ bo, const int* __restrict__ gnp,
    unsigned long long* __restrict__ best)
{
  const int t = 64 + blockIdx.y;
  if (t < gnp[0]) return;
  const int vt   = blockIdx.x;     // [0,8)
  const int z    = blockIdx.z;     // [0,4) b-quarter
  const int tid  = threadIdx.x;
  const int w    = tid >> 6;
  const int lane = tid & 63;

  int v[4], vc[4]; bool val[4];
  #pragma unroll
  for (int vj = 0; vj < 4; ++vj) {
    v[vj]  = vt*1024 + vj*256 + tid;
    val[vj] = (v[vj] < VV);          // wave-uniform (boundary multiple of 64)
    vc[vj] = val[vj] ? v[vj] : (VV-1);
  }

  __shared__ float hds[128*16];     // 8 KB: h chunk [128 k][16 b]
  __shared__ unsigned long long red[4][16];

  float tot[64], reg[64];           // [vj*16 + bb]: panel totals + current panel
  #pragma unroll
  for (int i = 0; i < 64; ++i) { tot[i] = 0.f; reg[i] = 0.f; }

  const float* hf = hist + (size_t)(t-64)*(HH*BB);

  #pragma unroll 1
  for (int kc8 = 0; kc8 < 8; ++kc8) {
    __syncthreads();
    #pragma unroll
    for (int s = 0; s < 8; ++s) {
      int idx = s*256 + tid;
      int kl = idx >> 4, bb = idx & 15;
      hds[idx] = hf[(size_t)(kc8*128 + kl)*BB + z*16 + bb];
    }
    __syncthreads();
    #pragma unroll 1
    for (int sub = 0; sub < 4; ++sub) {
      int kabs = kc8*128 + sub*32;
      if (kabs == 288 || kabs == 576 || kabs == 864) {   // Eigen C += panel
        #pragma unroll
        for (int i = 0; i < 64; ++i) { tot[i] = __fadd_rn(tot[i], reg[i]); reg[i] = 0.f; }
      }
      #pragma unroll 2
      for (int k = sub*32; k < sub*32 + 32; ++k) {
        const float* wr = Wo + (size_t)(kc8*128 + k)*VV;
        float wv0 = wr[vc[0]], wv1 = wr[vc[1]], wv2 = wr[vc[2]], wv3 = wr[vc[3]];
        #pragma unroll
        for (int bb = 0; bb < 16; ++bb) {
          float hb = hds[k*16 + bb];
          reg[0*16+bb] = __fadd_rn(reg[0*16+bb], __fmul_rn(hb, wv0));
          reg[1*16+bb] = __fadd_rn(reg[1*16+bb], __fmul_rn(hb, wv1));
          reg[2*16+bb] = __fadd_rn(reg[2*16+bb], __fmul_rn(hb, wv2));
          reg[3*16+bb] = __fadd_rn(reg[3*16+bb], __fmul_rn(hb, wv3));
        }
      }
    }
  }
  // final panel fold
  #pragma unroll
  for (int i = 0; i < 64; ++i) tot[i] = __fadd_rn(tot[i], reg[i]);

  uint32_t kt0, kt1;
  tf2x32(0u, 1u, 0u, (uint32_t)t, kt0, kt1);   // subkey = split(key(1))[t]
  float bov[4];
  #pragma unroll
  for (int vj = 0; vj < 4; ++vj) bov[vj] = val[vj] ? bo[v[vj]] : 0.f;

  #pragma unroll 1
  for (int bb = 0; bb < 16; ++bb) {
    int bglob = z*16 + bb;
    unsigned long long pm = 0ull;
    #pragma unroll
    for (int vj = 0; vj < 4; ++vj) {
      if (val[vj]) {
        uint32_t y0, y1;
        tf2x32(kt0, kt1, 0u, (uint32_t)(bglob*VV + v[vj]), y0, y1);
        float u  = u01f(y0 ^ y1);
        float l1 = logf(u);
        float l2 = logf(-l1);
        float g  = -l2;
        float L  = __fadd_rn(tot[vj*16 + bb], bov[vj]);   // logits = fl(hWo + bo)
        float sc = __fadd_rn(g, L);                        // fl(gumbel + logits)
        unsigned long long p = pack32(sc, v[vj]);
        if (p > pm) pm = p;
      }
    }
    #pragma unroll
    for (int m = 32; m > 0; m >>= 1) {
      unsigned long long q = __shfl_xor(pm, m);
      if (q > pm) pm = q;
    }
    if (lane == 0) red[w][bb] = pm;
    __syncthreads();
    if (tid == 0) {
      unsigned long long m0 = red[0][bb];
      if (red[1][bb] > m0) m0 = red[1][bb];
      if (red[2][bb] > m0) m0 = red[2][bb];
      if (red[3][bb] > m0) m0 = red[3][bb];
      atomicMax(&best[(size_t)t*BB + z*16 + bb], m0);
    }
    __syncthreads();
  }
}

// ---------------- finalize ----------------
__global__ void finalize(const int* __restrict__ x, const int* __restrict__ gnp,
                         const unsigned long long* __restrict__ best, int* __restrict__ out)
{
  int i = blockIdx.x*256 + threadIdx.x;
  if (i >= BB*TT) return;
  int t = i & 127;
  int b = i >> 7;
  if (t < gnp[0] || t < 64) out[i] = x[i];
  else out[i] = 8191 - (int)(best[(size_t)t*BB + b] & 0x1FFFull);
}

// ---------------- launch ----------------
extern "C" void kernel_launch(void* const* d_in, const int* in_sizes, int n_in,
                              void* d_out, int out_size, void* d_ws, size_t ws_size,
                              hipStream_t stream)
{
  const int*   x    = (const int*)  d_in[0];
  const int*   gn   = (const int*)  d_in[1];
  const float* emb  = (const float*)d_in[2];
  const float* Wi   = (const float*)d_in[3];
  const float* Ui   = (const float*)d_in[4];
  const float* bi   = (const float*)d_in[5];
  const float* Wf   = (const float*)d_in[6];
  const float* Uf   = (const float*)d_in[7];
  const float* bf   = (const float*)d_in[8];
  const float* Wog  = (const float*)d_in[9];
  const float* Uog  = (const float*)d_in[10];
  const float* bog  = (const float*)d_in[11];
  const float* Wc   = (const float*)d_in[12];
  const float* Uc   = (const float*)d_in[13];
  const float* bc   = (const float*)d_in[14];
  const float* Wo   = (const float*)d_in[15];
  const float* bo   = (const float*)d_in[16];

  // ws layout: Ut 16MB | Wt 4MB | ring 512KB | hist 16MB | best 64KB
  float* Ut   = (float*)d_ws;                              // 4Mi floats
  float* Wt   = Ut + (size_t)4*1024*1024;                  // 1Mi floats
  float* ring = Wt + (size_t)1024*1024;                    // 2*65536 floats
  float* hist = ring + (size_t)2*HH*BB;                    // 64*65536 floats
  unsigned long long* best =
      (unsigned long long*)(hist + (size_t)64*HH*BB);      // 128*64 u64

  initz<<<512, 256, 0, stream>>>(ring, best);
  transpose4f<<<dim3(256,4), 256, 0, stream>>>(Ui, Uf, Uog, Uc, Ut, 1024, 1024);
  transpose4f<<<dim3(64,4),  256, 0, stream>>>(Wi, Wf, Wog, Wc, Wt, 256, 1024);

  const int* xp = x; const float* embp = emb; const float* Wtp = Wt; const float* Utp = Ut;
  const float* bip = bi; const float* bfp = bf; const float* bogp = bog; const float* bcp = bc;
  float* ringp = ring; float* histp = hist;
  void* kargs[] = { (void*)&xp, (void*)&embp, (void*)&Wtp, (void*)&Utp,
                    (void*)&bip, (void*)&bfp, (void*)&bogp, (void*)&bcp,
                    (void*)&ringp, (void*)&histp };
  hipLaunchCooperativeKernel((void*)lstm_rec, dim3(256), dim3(256), kargs, 0, stream);

  logits_samp<<<dim3(8,64,4), 256, 0, stream>>>(hist, Wo, bo, gn, best);
  finalize<<<32, 256, 0, stream>>>(x, gn, best, (int*)d_out);
}

// Round 6
// 8309.187 us; speedup vs baseline: 1.3453x; 1.3453x over previous
//
#include <hip/hip_runtime.h>
#include <hip/hip_cooperative_groups.h>
#include <cstdint>
#include <cstddef>

#define TT 128
#define BB 64
#define EE 256
#define HH 1024
#define VV 8000
#define LSTRIDE 132   // LDS row stride: 16B-aligned, 4i-bank starts (optimal b128)

// ---------------- threefry2x32 (20 rounds), bit-exact vs JAX partitionable ----------------
__device__ __forceinline__ uint32_t rotl32(uint32_t v, int r){ return (v<<r)|(v>>(32-r)); }

__device__ __forceinline__ void tf2x32(uint32_t k0, uint32_t k1, uint32_t x0, uint32_t x1,
                                       uint32_t& y0, uint32_t& y1)
{
  const uint32_t k2 = k0 ^ k1 ^ 0x1BD11BDAu;
  x0 += k0; x1 += k1;
#define TFR(r) { x0 += x1; x1 = rotl32(x1,(r)); x1 ^= x0; }
  TFR(13) TFR(15) TFR(26) TFR(6)   x0 += k1; x1 += k2 + 1u;
  TFR(17) TFR(29) TFR(16) TFR(24)  x0 += k2; x1 += k0 + 2u;
  TFR(13) TFR(15) TFR(26) TFR(6)   x0 += k0; x1 += k1 + 3u;
  TFR(17) TFR(29) TFR(16) TFR(24)  x0 += k1; x1 += k2 + 4u;
  TFR(13) TFR(15) TFR(26) TFR(6)   x0 += k2; x1 += k0 + 5u;
#undef TFR
  y0 = x0; y1 = x1;
}

// uniform in [tiny,1): bit-exact fp32 recipe of jax uniform(minval=tiny, maxval=1)
__device__ __forceinline__ float u01f(uint32_t bits){
  float f = __uint_as_float((bits >> 9) | 0x3f800000u) - 1.0f;
  return (f == 0.0f) ? 1.17549435e-38f : f;
}

// ---------------- XLA EmitFastTanh, non-FMA form (mul/add separate roundings) ------------
__device__ __forceinline__ float xla_tanh(float x){
  float xc = fminf(fmaxf(x, -7.90531110763549805f), 7.90531110763549805f);
  float x2 = __fmul_rn(xc, xc);
  float num = -2.76076847742355e-16f;
  num = __fadd_rn(__fmul_rn(x2, num),  2.00018790482477e-13f);
  num = __fadd_rn(__fmul_rn(x2, num), -8.60467152213735e-11f);
  num = __fadd_rn(__fmul_rn(x2, num),  5.12229709037114e-08f);
  num = __fadd_rn(__fmul_rn(x2, num),  1.48572235717979e-05f);
  num = __fadd_rn(__fmul_rn(x2, num),  6.37261928875436e-04f);
  num = __fadd_rn(__fmul_rn(x2, num),  4.89352455891786e-03f);
  num = __fmul_rn(xc, num);
  float den = 1.19825839466702e-06f;
  den = __fadd_rn(__fmul_rn(x2, den), 1.18534705686654e-04f);
  den = __fadd_rn(__fmul_rn(x2, den), 2.26843463243900e-03f);
  den = __fadd_rn(__fmul_rn(x2, den), 4.89352518554385e-03f);
  float r = __fdiv_rn(num, den);
  return (fabsf(x) < 0.0004f) ? x : r;
}

// XLA LogisticExpander: logistic(x) = 0.5 + 0.5*tanh(0.5*x), separate roundings
__device__ __forceinline__ float xla_sigmoid(float x){
  float t = xla_tanh(__fmul_rn(0.5f, x));
  return __fadd_rn(0.5f, __fmul_rn(0.5f, t));
}

// pack fp32 score + v; ties -> smaller v (first-max, matching jnp.argmax)
__device__ __forceinline__ unsigned long long pack32(float s, int v){
  uint32_t u = __float_as_uint(s);
  u = (u >> 31) ? ~u : (u | 0x80000000u);
  return ((unsigned long long)u << 32) | (unsigned)(8191 - v);
}

// ---------------- init ----------------
__global__ void initz(float* ring, unsigned long long* best, int* flags){
  int i = blockIdx.x*256 + threadIdx.x;
  if (i < 2*HH*BB) ring[i] = 0.f;
  if (i < TT*BB)   best[i] = 0ull;
  if (i < 256)     flags[i] = 0;
}

// ---------------- px precompute: px[t][e][b] = emb[x[b][t]][e] ----------------
__global__ __launch_bounds__(256) void pxgen(
    const int* __restrict__ x, const float* __restrict__ emb, float* __restrict__ px)
{
  int flat = blockIdx.x*256 + threadIdx.x;      // 128*256*64 = 2M
  int b = flat & 63;
  int e = (flat >> 6) & 255;
  int t = flat >> 14;
  if (t >= TT) return;
  int tok = x[b*TT + t];
  px[((size_t)t*EE + e)*BB + b] = emb[(size_t)tok*EE + e];
}

// ---------------- transpose 4 gate matrices: in [R][C] -> out[(g*C + c)*R + r] ----------------
__global__ __launch_bounds__(256) void transpose4f(
    const float* __restrict__ g0, const float* __restrict__ g1,
    const float* __restrict__ g2, const float* __restrict__ g3,
    float* __restrict__ out, int R, int C)
{
  const float* in = (blockIdx.y==0)?g0:(blockIdx.y==1)?g1:(blockIdx.y==2)?g2:g3;
  int tilesC = C >> 6;
  int tr = blockIdx.x / tilesC, tc = blockIdx.x % tilesC;
  __shared__ float tile[64][65];
  int tid = threadIdx.x;
  #pragma unroll
  for (int s = 0; s < 16; ++s) {
    int li = s*256 + tid;
    int r = li >> 6, c = li & 63;
    tile[r][c] = in[(size_t)(tr*64 + r)*C + tc*64 + c];
  }
  __syncthreads();
  #pragma unroll
  for (int s = 0; s < 16; ++s) {
    int li = s*256 + tid;
    int c = li >> 6, r = li & 63;
    out[((size_t)blockIdx.y*C + tc*64 + c)*R + tr*64 + r] = tile[r][c];
  }
}

// ---------------- cooperative LSTM recurrence: XLA-CPU faithful, fast transport -----------
// 256 blocks x 512 threads (8 waves). Wave w: p = w>>1 -> jc = bid*4+p; half = w&1 ->
// gates {i,f} (half0) or {og,c} (half1). Lanes = batch b. Each gate's mul/add chain is
// computed end-to-end by one thread => exact reference rounding (xw chain e=0..255;
// hU panels folded at k=288/576/864). Cross-XCD h transport via device-scope (agent)
// atomics through L3; per-block flag barrier (no L2 flush => weights stay L2-hot).
__global__ __launch_bounds__(512, 2) void lstm_rec(
    const float* __restrict__ Wt, const float* __restrict__ Ut,
    const float* __restrict__ bi, const float* __restrict__ bf,
    const float* __restrict__ bog, const float* __restrict__ bc,
    const float* __restrict__ px, float* __restrict__ ring,
    float* __restrict__ hist, int* __restrict__ flags)
{
  __shared__ float sA[64*LSTRIDE];
  __shared__ float sB[64*LSTRIDE];
  __shared__ float spx[64*LSTRIDE];
  __shared__ float xch[512];

  const int tid  = threadIdx.x;
  const int w    = tid >> 6;
  const int lane = tid & 63;
  const int p    = w >> 1;
  const int half = w & 1;
  const int ju   = __builtin_amdgcn_readfirstlane(blockIdx.x*4 + p);
  const int g0   = 2*half, g1 = 2*half + 1;

  const float* U0 = Ut + ((size_t)g0*HH + ju)*HH;
  const float* U1 = Ut + ((size_t)g1*HH + ju)*HH;
  const float* W0 = Wt + ((size_t)g0*HH + ju)*EE;
  const float* W1 = Wt + ((size_t)g1*HH + ju)*EE;
  const float biaA = half ? bog[ju] : bi[ju];
  const float biaB = half ? bc[ju]  : bf[ju];

  float c = 0.f;
  float B0 = 0.f, B1 = 0.f;   // xw+bias for my 2 gates
  float4 pre[4];

  auto load_chunk = [&](const float* hp, int hcn){
    #pragma unroll
    for (int s = 0; s < 4; ++s) {
      int f = s*512 + tid;
      int k = f >> 4, b0 = (f & 15)*4;
      const unsigned long long* gp =
          (const unsigned long long*)(hp + (size_t)(hcn*128 + k)*BB + b0);
      unsigned long long a0 = __hip_atomic_load(gp,   __ATOMIC_RELAXED, __HIP_MEMORY_SCOPE_AGENT);
      unsigned long long a1 = __hip_atomic_load(gp+1, __ATOMIC_RELAXED, __HIP_MEMORY_SCOPE_AGENT);
      pre[s].x = __uint_as_float((unsigned)a0);
      pre[s].y = __uint_as_float((unsigned)(a0 >> 32));
      pre[s].z = __uint_as_float((unsigned)a1);
      pre[s].w = __uint_as_float((unsigned)(a1 >> 32));
    }
  };
  auto store_chunk = [&](float* buf){
    #pragma unroll
    for (int s = 0; s < 4; ++s) {
      int f = s*512 + tid;
      int k = f >> 4, b0 = (f & 15)*4;
      buf[(b0+0)*LSTRIDE + k] = pre[s].x;
      buf[(b0+1)*LSTRIDE + k] = pre[s].y;
      buf[(b0+2)*LSTRIDE + k] = pre[s].z;
      buf[(b0+3)*LSTRIDE + k] = pre[s].w;
    }
  };

  // xw chains for my 2 gates at step t2 (exact e=0..255 mul/add order, then +bias)
  auto compute_xw = [&](int t2){
    float A0 = 0.f, A1 = 0.f;
    #pragma unroll 1
    for (int ch = 0; ch < 2; ++ch) {
      const float* pxc = px + ((size_t)t2*EE + ch*128)*BB;
      __syncthreads();
      #pragma unroll
      for (int s = 0; s < 4; ++s) {
        int f = s*512 + tid;
        int e = f >> 4, b0 = (f & 15)*4;
        float4 v = *(const float4*)(pxc + (size_t)e*BB + b0);
        spx[(b0+0)*LSTRIDE + e] = v.x;
        spx[(b0+1)*LSTRIDE + e] = v.y;
        spx[(b0+2)*LSTRIDE + e] = v.z;
        spx[(b0+3)*LSTRIDE + e] = v.w;
      }
      __syncthreads();
      #pragma unroll
      for (int e = 0; e < 128; e += 4) {
        float4 p4 = *(const float4*)&spx[lane*LSTRIDE + e];
        A0 = __fadd_rn(A0, __fmul_rn(p4.x, W0[ch*128 + e + 0]));
        A1 = __fadd_rn(A1, __fmul_rn(p4.x, W1[ch*128 + e + 0]));
        A0 = __fadd_rn(A0, __fmul_rn(p4.y, W0[ch*128 + e + 1]));
        A1 = __fadd_rn(A1, __fmul_rn(p4.y, W1[ch*128 + e + 1]));
        A0 = __fadd_rn(A0, __fmul_rn(p4.z, W0[ch*128 + e + 2]));
        A1 = __fadd_rn(A1, __fmul_rn(p4.z, W1[ch*128 + e + 2]));
        A0 = __fadd_rn(A0, __fmul_rn(p4.w, W0[ch*128 + e + 3]));
        A1 = __fadd_rn(A1, __fmul_rn(p4.w, W1[ch*128 + e + 3]));
      }
    }
    B0 = __fadd_rn(A0, biaA);
    B1 = __fadd_rn(A1, biaB);
  };

  compute_xw(0);   // prologue: xw for t=0

  #pragma unroll 1
  for (int t = 0; t < TT; ++t) {
    const float* hp = ring + (size_t)(t & 1)*(HH*BB);
    float*       rn = ring + (size_t)((t+1) & 1)*(HH*BB);

    // ---- h @ U: mul+add chains, Eigen kc=288 panels; LDS double-buffered ----
    load_chunk(hp, 0);
    float R0 = 0.f, R1 = 0.f, T0 = 0.f, T1 = 0.f;
    #pragma unroll 1
    for (int hc = 0; hc < 8; ++hc) {
      float* cur = (hc & 1) ? sB : sA;
      __syncthreads();
      store_chunk(cur);
      if (hc < 7) load_chunk(hp, hc + 1);
      __syncthreads();
      #pragma unroll
      for (int sub = 0; sub < 4; ++sub) {
        int kabs = hc*128 + sub*32;
        if (kabs == 288 || kabs == 576 || kabs == 864) {   // Eigen C += panel (CR add)
          T0 = __fadd_rn(T0, R0); R0 = 0.f;
          T1 = __fadd_rn(T1, R1); R1 = 0.f;
        }
        #pragma unroll
        for (int q = sub*32; q < sub*32 + 32; q += 4) {
          float4 h4 = *(const float4*)&cur[lane*LSTRIDE + q];
          R0 = __fadd_rn(R0, __fmul_rn(h4.x, U0[hc*128 + q + 0]));
          R1 = __fadd_rn(R1, __fmul_rn(h4.x, U1[hc*128 + q + 0]));
          R0 = __fadd_rn(R0, __fmul_rn(h4.y, U0[hc*128 + q + 1]));
          R1 = __fadd_rn(R1, __fmul_rn(h4.y, U1[hc*128 + q + 1]));
          R0 = __fadd_rn(R0, __fmul_rn(h4.z, U0[hc*128 + q + 2]));
          R1 = __fadd_rn(R1, __fmul_rn(h4.z, U1[hc*128 + q + 2]));
          R0 = __fadd_rn(R0, __fmul_rn(h4.w, U0[hc*128 + q + 3]));
          R1 = __fadd_rn(R1, __fmul_rn(h4.w, U1[hc*128 + q + 3]));
        }
      }
    }
    T0 = __fadd_rn(T0, R0);                 // final panel fold
    T1 = __fadd_rn(T1, R1);
    float z0 = __fadd_rn(B0, T0);           // z = fl(xw + hU)
    float z1 = __fadd_rn(B1, T1);

    // ---- gates: half1 computes tanh(zc), sig(zo); half0 computes sig(zi), sig(zf) ----
    float igv = 0.f, fgv = 0.f;
    if (half) {
      float th  = xla_tanh(z1);
      float ogs = xla_sigmoid(z0);
      xch[p*64 + lane]       = th;
      xch[256 + p*64 + lane] = ogs;
    } else {
      igv = xla_sigmoid(z0);
      fgv = xla_sigmoid(z1);
    }
    __syncthreads();
    if (!half) {
      float th  = xch[p*64 + lane];
      float ogs = xch[256 + p*64 + lane];
      c = __fadd_rn(__fmul_rn(fgv, c), __fmul_rn(igv, th));
      float hv = __fmul_rn(ogs, xla_tanh(c));
      size_t idx = (size_t)ju*BB + lane;
      __hip_atomic_store(&rn[idx], hv, __ATOMIC_RELAXED, __HIP_MEMORY_SCOPE_AGENT);
      if (t >= 64) hist[(size_t)(t-64)*(HH*BB) + idx] = hv;
    }
    __syncthreads();   // drain all waves' h stores (vmcnt0 before s_barrier)
    if (tid == 0)
      __hip_atomic_store(&flags[blockIdx.x], t+1, __ATOMIC_RELEASE, __HIP_MEMORY_SCOPE_AGENT);

    if (t < TT-1) {
      compute_xw(t+1);    // overlapped with other blocks finishing step t
      if (w == 0) {       // wave0 polls all 256 flags (4 per lane)
        for (;;) {
          int m0 = __hip_atomic_load(&flags[lane],       __ATOMIC_RELAXED, __HIP_MEMORY_SCOPE_AGENT);
          int m1 = __hip_atomic_load(&flags[64 + lane],  __ATOMIC_RELAXED, __HIP_MEMORY_SCOPE_AGENT);
          int m2 = __hip_atomic_load(&flags[128 + lane], __ATOMIC_RELAXED, __HIP_MEMORY_SCOPE_AGENT);
          int m3 = __hip_atomic_load(&flags[192 + lane], __ATOMIC_RELAXED, __HIP_MEMORY_SCOPE_AGENT);
          int mm = m0 < m1 ? m0 : m1;
          int nn = m2 < m3 ? m2 : m3;
          mm = mm < nn ? mm : nn;
          if (__all(mm >= t+1)) break;
          __builtin_amdgcn_s_sleep(1);
        }
        __atomic_signal_fence(__ATOMIC_ACQUIRE);
      }
      __syncthreads();
    }
  }
}

// ---------------- logits + gumbel argmax: XLA-CPU faithful (unchanged, verified) ----------
__global__ __launch_bounds__(256, 2) void logits_samp(
    const float* __restrict__ hist, const float* __restrict__ Wo,
    const float* __restrict__ bo, const int* __restrict__ gnp,
    unsigned long long* __restrict__ best)
{
  const int t = 64 + blockIdx.y;
  if (t < gnp[0]) return;
  const int vt   = blockIdx.x;     // [0,8)
  const int z    = blockIdx.z;     // [0,4) b-quarter
  const int tid  = threadIdx.x;
  const int w    = tid >> 6;
  const int lane = tid & 63;

  int v[4], vc[4]; bool val[4];
  #pragma unroll
  for (int vj = 0; vj < 4; ++vj) {
    v[vj]  = vt*1024 + vj*256 + tid;
    val[vj] = (v[vj] < VV);
    vc[vj] = val[vj] ? v[vj] : (VV-1);
  }

  __shared__ float hds[128*16];
  __shared__ unsigned long long red[4][16];

  float tot[64], reg[64];
  #pragma unroll
  for (int i = 0; i < 64; ++i) { tot[i] = 0.f; reg[i] = 0.f; }

  const float* hf = hist + (size_t)(t-64)*(HH*BB);

  #pragma unroll 1
  for (int kc8 = 0; kc8 < 8; ++kc8) {
    __syncthreads();
    #pragma unroll
    for (int s = 0; s < 8; ++s) {
      int idx = s*256 + tid;
      int kl = idx >> 4, bb = idx & 15;
      hds[idx] = hf[(size_t)(kc8*128 + kl)*BB + z*16 + bb];
    }
    __syncthreads();
    #pragma unroll 1
    for (int sub = 0; sub < 4; ++sub) {
      int kabs = kc8*128 + sub*32;
      if (kabs == 288 || kabs == 576 || kabs == 864) {
        #pragma unroll
        for (int i = 0; i < 64; ++i) { tot[i] = __fadd_rn(tot[i], reg[i]); reg[i] = 0.f; }
      }
      #pragma unroll 2
      for (int k = sub*32; k < sub*32 + 32; ++k) {
        const float* wr = Wo + (size_t)(kc8*128 + k)*VV;
        float wv0 = wr[vc[0]], wv1 = wr[vc[1]], wv2 = wr[vc[2]], wv3 = wr[vc[3]];
        #pragma unroll
        for (int bb = 0; bb < 16; ++bb) {
          float hb = hds[k*16 + bb];
          reg[0*16+bb] = __fadd_rn(reg[0*16+bb], __fmul_rn(hb, wv0));
          reg[1*16+bb] = __fadd_rn(reg[1*16+bb], __fmul_rn(hb, wv1));
          reg[2*16+bb] = __fadd_rn(reg[2*16+bb], __fmul_rn(hb, wv2));
          reg[3*16+bb] = __fadd_rn(reg[3*16+bb], __fmul_rn(hb, wv3));
        }
      }
    }
  }
  #pragma unroll
  for (int i = 0; i < 64; ++i) tot[i] = __fadd_rn(tot[i], reg[i]);

  uint32_t kt0, kt1;
  tf2x32(0u, 1u, 0u, (uint32_t)t, kt0, kt1);
  float bov[4];
  #pragma unroll
  for (int vj = 0; vj < 4; ++vj) bov[vj] = val[vj] ? bo[v[vj]] : 0.f;

  #pragma unroll 1
  for (int bb = 0; bb < 16; ++bb) {
    int bglob = z*16 + bb;
    unsigned long long pm = 0ull;
    #pragma unroll
    for (int vj = 0; vj < 4; ++vj) {
      if (val[vj]) {
        uint32_t y0, y1;
        tf2x32(kt0, kt1, 0u, (uint32_t)(bglob*VV + v[vj]), y0, y1);
        float u  = u01f(y0 ^ y1);
        float l1 = logf(u);
        float l2 = logf(-l1);
        float g  = -l2;
        float L  = __fadd_rn(tot[vj*16 + bb], bov[vj]);
        float sc = __fadd_rn(g, L);
        unsigned long long pk = pack32(sc, v[vj]);
        if (pk > pm) pm = pk;
      }
    }
    #pragma unroll
    for (int m = 32; m > 0; m >>= 1) {
      unsigned long long q = __shfl_xor(pm, m);
      if (q > pm) pm = q;
    }
    if (lane == 0) red[w][bb] = pm;
    __syncthreads();
    if (tid == 0) {
      unsigned long long m0 = red[0][bb];
      if (red[1][bb] > m0) m0 = red[1][bb];
      if (red[2][bb] > m0) m0 = red[2][bb];
      if (red[3][bb] > m0) m0 = red[3][bb];
      atomicMax(&best[(size_t)t*BB + z*16 + bb], m0);
    }
    __syncthreads();
  }
}

// ---------------- finalize ----------------
__global__ void finalize(const int* __restrict__ x, const int* __restrict__ gnp,
                         const unsigned long long* __restrict__ best, int* __restrict__ out)
{
  int i = blockIdx.x*256 + threadIdx.x;
  if (i >= BB*TT) return;
  int t = i & 127;
  int b = i >> 7;
  if (t < gnp[0] || t < 64) out[i] = x[i];
  else out[i] = 8191 - (int)(best[(size_t)t*BB + b] & 0x1FFFull);
}

// ---------------- launch ----------------
extern "C" void kernel_launch(void* const* d_in, const int* in_sizes, int n_in,
                              void* d_out, int out_size, void* d_ws, size_t ws_size,
                              hipStream_t stream)
{
  const int*   x    = (const int*)  d_in[0];
  const int*   gn   = (const int*)  d_in[1];
  const float* emb  = (const float*)d_in[2];
  const float* Wi   = (const float*)d_in[3];
  const float* Ui   = (const float*)d_in[4];
  const float* bi   = (const float*)d_in[5];
  const float* Wf   = (const float*)d_in[6];
  const float* Uf   = (const float*)d_in[7];
  const float* bf   = (const float*)d_in[8];
  const float* Wog  = (const float*)d_in[9];
  const float* Uog  = (const float*)d_in[10];
  const float* bog  = (const float*)d_in[11];
  const float* Wc   = (const float*)d_in[12];
  const float* Uc   = (const float*)d_in[13];
  const float* bc   = (const float*)d_in[14];
  const float* Wo   = (const float*)d_in[15];
  const float* bo   = (const float*)d_in[16];

  // ws: Ut 16MB | Wt 4MB | ring 512KB | hist 16MB | px 8MB | best 64KB | flags 1KB
  float* Ut   = (float*)d_ws;                              // 4Mi floats
  float* Wt   = Ut + (size_t)4*1024*1024;                  // 1Mi floats
  float* ring = Wt + (size_t)1024*1024;                    // 2*65536 floats
  float* hist = ring + (size_t)2*HH*BB;                    // 64*65536 floats
  float* px   = hist + (size_t)64*HH*BB;                   // 128*256*64 floats
  unsigned long long* best =
      (unsigned long long*)(px + (size_t)TT*EE*BB);        // 8192 u64
  int* flags  = (int*)(best + (size_t)TT*BB);              // 256 int

  initz<<<512, 256, 0, stream>>>(ring, best, flags);
  transpose4f<<<dim3(256,4), 256, 0, stream>>>(Ui, Uf, Uog, Uc, Ut, 1024, 1024);
  transpose4f<<<dim3(64,4),  256, 0, stream>>>(Wi, Wf, Wog, Wc, Wt, 256, 1024);
  pxgen<<<8192, 256, 0, stream>>>(x, emb, px);

  const float* Wtp = Wt; const float* Utp = Ut;
  const float* bip = bi; const float* bfp = bf; const float* bogp = bog; const float* bcp = bc;
  const float* pxp = px; float* ringp = ring; float* histp = hist; int* flagsp = flags;
  void* kargs[] = { (void*)&Wtp, (void*)&Utp,
                    (void*)&bip, (void*)&bfp, (void*)&bogp, (void*)&bcp,
                    (void*)&pxp, (void*)&ringp, (void*)&histp, (void*)&flagsp };
  hipLaunchCooperativeKernel((void*)lstm_rec, dim3(256), dim3(512), kargs, 0, stream);

  logits_samp<<<dim3(8,64,4), 256, 0, stream>>>(hist, Wo, bo, gn, best);
  finalize<<<32, 256, 0, stream>>>(x, gn, best, (int*)d_out);
}